// Round 1
// baseline (12156.694 us; speedup 1.0000x reference)
//
#include <hip/hip_runtime.h>

#define D 64

// out[row[e]] += val[e] * x[col[e]], x split across two arrays at `split`
// 16 lanes per edge, float4 per lane.
__global__ __launch_bounds__(256) void spmm_scatter(
    const int* __restrict__ rows, const int* __restrict__ cols,
    const float* __restrict__ vals,
    const float* __restrict__ srcA, const float* __restrict__ srcB, int split,
    float* __restrict__ out, int nedges)
{
    long long t = (long long)blockIdx.x * blockDim.x + threadIdx.x;
    int e = (int)(t >> 4);
    int l = (int)(t & 15);
    if (e >= nedges) return;
    int col = cols[e];
    int row = rows[e];
    float v = vals[e];
    const float* src = (col < split) ? (srcA + (size_t)col * D)
                                     : (srcB + (size_t)(col - split) * D);
    float4 x = *(const float4*)(src + l * 4);
    float* o = out + (size_t)row * D + l * 4;
    unsafeAtomicAdd(o + 0, v * x.x);
    unsafeAtomicAdd(o + 1, v * x.y);
    unsafeAtomicAdd(o + 2, v * x.z);
    unsafeAtomicAdd(o + 3, v * x.w);
}

// out[i] = out[i] + buf[i] + e0[i]   (e0 = concat(u, it)), float4-vectorized
__global__ __launch_bounds__(256) void add3(
    float* __restrict__ out, const float* __restrict__ buf,
    const float* __restrict__ u, const float* __restrict__ it,
    int user, long long nvec)
{
    long long t = (long long)blockIdx.x * blockDim.x + threadIdx.x;
    if (t >= nvec) return;
    long long i = t * 4;               // float index
    long long node = i / D;
    const float4 e0 = (node < user)
        ? *(const float4*)(u + i)
        : *(const float4*)(it + (i - (long long)user * D));
    float4 a = ((const float4*)out)[t];
    float4 b = ((const float4*)buf)[t];
    float4 r;
    r.x = a.x + b.x + e0.x;
    r.y = a.y + b.y + e0.y;
    r.z = a.z + b.z + e0.z;
    r.w = a.w + b.w + e0.w;
    ((float4*)out)[t] = r;
}

extern "C" void kernel_launch(void* const* d_in, const int* in_sizes, int n_in,
                              void* d_out, int out_size, void* d_ws, size_t ws_size,
                              hipStream_t stream) {
    const int*   rows = (const int*)  d_in[0];
    const int*   cols = (const int*)  d_in[1];
    const float* vals = (const float*)d_in[2];
    const float* u    = (const float*)d_in[3];
    const float* it   = (const float*)d_in[4];

    const int nedges = in_sizes[0];
    const int user   = in_sizes[3] / D;
    const int item   = in_sizes[4] / D;
    const long long nfloat = (long long)(user + item) * D;   // == out_size
    const size_t nbytes = (size_t)nfloat * sizeof(float);

    float* out = (float*)d_out;
    float* buf = (float*)d_ws;   // one N*D fp32 scratch buffer

    hipMemsetAsync(out, 0, nbytes, stream);
    hipMemsetAsync(buf, 0, nbytes, stream);

    const int spmm_threads = 256;
    const long long spmm_total = (long long)nedges * 16;
    const int spmm_blocks = (int)((spmm_total + spmm_threads - 1) / spmm_threads);

    // out = e1  (gather from split u/it arrays)
    spmm_scatter<<<spmm_blocks, spmm_threads, 0, stream>>>(
        rows, cols, vals, u, it, user, out, nedges);

    // buf = e2  (gather from contiguous out)
    spmm_scatter<<<spmm_blocks, spmm_threads, 0, stream>>>(
        rows, cols, vals, out, out + (size_t)user * D, user, buf, nedges);

    // out = e0 + e1 + e2
    const long long nvec = nfloat / 4;
    const int add_blocks = (int)((nvec + 255) / 256);
    add3<<<add_blocks, 256, 0, stream>>>(out, buf, u, it, user, nvec);

    // out += e3  (spmm from buf, atomically accumulate into out)
    spmm_scatter<<<spmm_blocks, spmm_threads, 0, stream>>>(
        rows, cols, vals, buf, buf + (size_t)user * D, user, out, nedges);
}

// Round 2
// 1062.560 us; speedup vs baseline: 11.4410x; 11.4410x over previous
//
#include <hip/hip_runtime.h>

#define D 64
#define SCAN_T 256
#define SCAN_E 4
#define CHUNK (SCAN_T * SCAN_E)   // 1024 elements per scan block

// ---------- CSR build ----------

__global__ __launch_bounds__(256) void hist_rows(
    const int* __restrict__ rows, int* __restrict__ cnt, int nedges)
{
    int e = blockIdx.x * 256 + threadIdx.x;
    if (e < nedges) atomicAdd(&cnt[rows[e]], 1);
}

// per-chunk exclusive scan (in-place) + chunk totals
__global__ __launch_bounds__(SCAN_T) void scan_chunks(
    int* __restrict__ A, int n, int* __restrict__ bsums)
{
    __shared__ int lds[SCAN_T];
    int t = threadIdx.x;
    int base = blockIdx.x * CHUNK + t * SCAN_E;
    int v[SCAN_E];
    int s = 0;
    #pragma unroll
    for (int i = 0; i < SCAN_E; i++) { v[i] = (base + i < n) ? A[base + i] : 0; s += v[i]; }
    lds[t] = s;
    __syncthreads();
    for (int ofs = 1; ofs < SCAN_T; ofs <<= 1) {
        int x = (t >= ofs) ? lds[t - ofs] : 0;
        __syncthreads();
        lds[t] += x;
        __syncthreads();
    }
    if (t == SCAN_T - 1) bsums[blockIdx.x] = lds[t];
    int run = lds[t] - s;   // exclusive prefix of this thread within block
    #pragma unroll
    for (int i = 0; i < SCAN_E; i++) { int x = v[i]; if (base + i < n) A[base + i] = run; run += x; }
}

// single-block exclusive scan of chunk totals (nb <= 1024)
__global__ __launch_bounds__(1024) void scan_bsums(int* __restrict__ bsums, int nb)
{
    __shared__ int lds[1024];
    int t = threadIdx.x;
    int v = (t < nb) ? bsums[t] : 0;
    lds[t] = v;
    __syncthreads();
    for (int ofs = 1; ofs < 1024; ofs <<= 1) {
        int x = (t >= ofs) ? lds[t - ofs] : 0;
        __syncthreads();
        lds[t] += x;
        __syncthreads();
    }
    if (t < nb) bsums[t] = lds[t] - v;
}

__global__ __launch_bounds__(SCAN_T) void add_bsums(
    int* __restrict__ A, int n, const int* __restrict__ bsums)
{
    int t = threadIdx.x;
    int base = blockIdx.x * CHUNK + t * SCAN_E;
    int add = bsums[blockIdx.x];
    #pragma unroll
    for (int i = 0; i < SCAN_E; i++) if (base + i < n) A[base + i] += add;
}

// scatter edges into CSR order; bumps A[r] from rowptr[r] to rowptr[r+1]
__global__ __launch_bounds__(256) void scatter_edges(
    const int* __restrict__ rows, const int* __restrict__ cols,
    const float* __restrict__ vals, int* __restrict__ cur,
    int2* __restrict__ pairs, int nedges)
{
    int e = blockIdx.x * 256 + threadIdx.x;
    if (e >= nedges) return;
    int p = atomicAdd(&cur[rows[e]], 1);
    pairs[p] = make_int2(cols[e], __float_as_int(vals[e]));
}

// ---------- gather-style CSR spmm ----------
// After scatter, endp[r] == rowptr[r+1]; start of row r is endp[r-1] (0 for r==0).
// 16 lanes per row, float4 per lane. Source is split at `split` (srcA/srcB).
// FUSED: out[row] = e0[row] + out[row](=e1) + prev[row](=e2) + spmm(prev)[row]
template <bool FUSED>
__global__ __launch_bounds__(256) void spmm_csr(
    const int* __restrict__ endp, const int2* __restrict__ pairs,
    const float* __restrict__ srcA, const float* __restrict__ srcB, int split,
    const float* __restrict__ u, const float* __restrict__ it, int user,
    const float* __restrict__ prev, float* __restrict__ out, int n)
{
    int row = blockIdx.x * 16 + (threadIdx.x >> 4);
    if (row >= n) return;
    int l = threadIdx.x & 15;
    int start = row ? endp[row - 1] : 0;
    int end = endp[row];
    float ax = 0.f, ay = 0.f, az = 0.f, aw = 0.f;
    for (int e = start; e < end; ++e) {
        int2 p = pairs[e];
        int col = p.x;
        float v = __int_as_float(p.y);
        const float* src = (col < split) ? srcA + (size_t)col * D
                                         : srcB + (size_t)(col - split) * D;
        float4 x = *(const float4*)(src + l * 4);
        ax = fmaf(v, x.x, ax);
        ay = fmaf(v, x.y, ay);
        az = fmaf(v, x.z, az);
        aw = fmaf(v, x.w, aw);
    }
    float* o = out + (size_t)row * D + l * 4;
    if (FUSED) {
        const float* e0 = (row < user) ? u + (size_t)row * D
                                       : it + (size_t)(row - user) * D;
        float4 b0 = *(const float4*)(e0 + l * 4);
        float4 b1 = *(const float4*)o;                               // e1
        float4 b2 = *(const float4*)(prev + (size_t)row * D + l * 4); // e2
        ax += b0.x + b1.x + b2.x;
        ay += b0.y + b1.y + b2.y;
        az += b0.z + b1.z + b2.z;
        aw += b0.w + b1.w + b2.w;
    }
    *(float4*)o = make_float4(ax, ay, az, aw);
}

// ---------- launch ----------

static inline size_t alignup(size_t x) { return (x + 255) & ~(size_t)255; }

extern "C" void kernel_launch(void* const* d_in, const int* in_sizes, int n_in,
                              void* d_out, int out_size, void* d_ws, size_t ws_size,
                              hipStream_t stream) {
    const int*   rows = (const int*)  d_in[0];
    const int*   cols = (const int*)  d_in[1];
    const float* vals = (const float*)d_in[2];
    const float* u    = (const float*)d_in[3];
    const float* it   = (const float*)d_in[4];

    const int nedges = in_sizes[0];
    const int user   = in_sizes[3] / D;
    const int item   = in_sizes[4] / D;
    const int n      = user + item;

    float* out = (float*)d_out;

    // workspace carve
    char* w = (char*)d_ws;
    int*  A     = (int*)w;  w += alignup((size_t)n * sizeof(int));
    int*  bsums = (int*)w;  w += alignup(4096);
    int2* pairs = (int2*)w; w += alignup((size_t)nedges * sizeof(int2));
    float* buf2 = (float*)w;  // n * D floats

    const int nb = (n + CHUNK - 1) / CHUNK;           // scan blocks (293 <= 1024)
    const int eblocks = (nedges + 255) / 256;
    const int sblocks = (n + 15) / 16;

    // CSR build
    hipMemsetAsync(A, 0, (size_t)n * sizeof(int), stream);
    hist_rows<<<eblocks, 256, 0, stream>>>(rows, A, nedges);
    scan_chunks<<<nb, SCAN_T, 0, stream>>>(A, n, bsums);
    scan_bsums<<<1, 1024, 0, stream>>>(bsums, nb);
    add_bsums<<<nb, SCAN_T, 0, stream>>>(A, n, bsums);
    scatter_edges<<<eblocks, 256, 0, stream>>>(rows, cols, vals, A, pairs, nedges);

    // out = e1 = spmm(e0), gather from split u/it
    spmm_csr<false><<<sblocks, 256, 0, stream>>>(
        A, pairs, u, it, user, nullptr, nullptr, user, nullptr, out, n);
    // buf2 = e2 = spmm(e1)
    spmm_csr<false><<<sblocks, 256, 0, stream>>>(
        A, pairs, out, out + (size_t)user * D, user, nullptr, nullptr, user, nullptr, buf2, n);
    // out = e0 + e1 + e2 + spmm(e2)
    spmm_csr<true><<<sblocks, 256, 0, stream>>>(
        A, pairs, buf2, buf2 + (size_t)user * D, user, u, it, user, buf2, out, n);
}